// Round 3
// baseline (162.431 us; speedup 1.0000x reference)
//
#include <hip/hip_runtime.h>

// Detection post-process: softmax -> decode -> per-class LAZY NMS -> top-100.
// N=8 images, A=16384 anchors, C=21 classes (class 0 = background).
//
// R8 finding (counters): top-5 = __amd_rocclr_fillBufferAligned 41us x2, 256 MiB
// @ 6.5 TB/s -- the harness ws re-poison is INSIDE the measured stream. ~82us of
// every dur_us is fixed; controllable kernel+gap budget is only ~60us. R1 cross-
// check: 60.4 (nms hw) + 82 (fills) = 142.4 ~= 143.9 measured.
// R9: minimize dispatches + serial latency: (1) re-fuse select+walk (kills one
// launch + keyg round-trip + duplicate gather), (2) TN 512->256, sort-512 as
// 2 keys/thread (LDS stages 6->3, lighter barriers), (3) walk prefetch depth 2
// (hides 120cyc LDS latency fully), (4) topk folded into nms via last-block-per-
// image (threadfence + device atomicAdd on imgctr; the 20th block runs the 2048
// bitonic with 8 keys/thread). 4 dispatches/iter -> 2.
// Exactness invariants (absmax 0.0 since R1):
//   - u64 key = (score_bits<<32)|~idx  => exact (score desc, idx asc) total order
//   - monotone bin(float bits) => bin-threshold selection is a key-order cut
//   - chunk = ALL keys in bins >= B; after chunk, filter = last popped key and
//     remaining candidates are exactly keys < filter (refill semantics unchanged)
//   - lazy NMS: dead entries never kill => test pops against accepted set only
//   - division-free EXACT IoU predicate:
//     RN_f32(inter/un) > 0.45f  <=>  (double)inter > ((double)0.45f + 2^-26)*(double)un
//   - topk key = (score_bits<<32)|(0xFFFFFFFF-(flat_j+100)) => exact lax.top_k order

typedef unsigned long long u64;

#define N_IMG 8
#define A     16384
#define NCLS  21
#define NC    20
#define TOPK  100
#define PROB_THR 0.05f

#define TN     256         // nms threads (4 waves)
#define NSLOT  64          // scores per thread
#define NBIN   1152        // score-bit bins: (bits>>15)-31385 spans (0.05,1]
#define BINOFF 31385
#define CAPC   512         // chunk capacity (sorted); expected pops ~150-250
#define TARGET 384

#define PHYS(i) ((i) + ((i) >> 4))   // LDS u64 swizzle: breaks power-of-2 strides

#define MIDTHR ((double)0.45f + 0x1p-26)

// anchor index for slot t of thread tid (float4 load pattern, TN=256)
#define AIDX(t_) ((tid << 2) + (((t_) >> 2) << 10) + ((t_) & 3))

__device__ __forceinline__ u64 pk(float v, int i) {
    return (v > 0.f) ? (((u64)__float_as_uint(v) << 32) | (u64)(unsigned)(~(unsigned)i)) : 0ull;
}
__device__ __forceinline__ float upv(u64 k) { return __uint_as_float((unsigned)(k >> 32)); }
__device__ __forceinline__ int   upi(u64 k) { return (int)(~(unsigned)k); }
__device__ __forceinline__ u64 umx(u64 a, u64 b) { return a > b ? a : b; }
__device__ __forceinline__ u64 umn(u64 a, u64 b) { return a < b ? a : b; }

// bitonic compare-exchange keep-rule for element i at stage (k,j)
__device__ __forceinline__ u64 bsel(u64 mine, u64 other, int i, int k, int j) {
    bool keep_max = ((i & k) == 0) == ((i & j) == 0);
    return keep_max ? umx(mine, other) : umn(mine, other);
}

__device__ __forceinline__ int binOf(float s) {
    int b = (int)(__float_as_uint(s) >> 15) - BINOFF;
    return b < 0 ? 0 : (b > NBIN - 1 ? NBIN - 1 : b);
}

// exact ref predicate: RN(inter/union) > 0.45f
__device__ __forceinline__ bool killp(float4 b, float ab, float4 s, float as_) {
    float lx = fmaxf(s.x, b.x), ly = fmaxf(s.y, b.y);
    float rx = fminf(s.z, b.z), ry = fminf(s.w, b.w);
    float iw = fmaxf(rx - lx, 0.f), ih = fmaxf(ry - ly, 0.f);
    float inter = iw * ih;
    float un = as_ + ab - inter;
    return (double)inter > MIDTHR * (double)un;
}

struct SMem {
    union {
        struct {
            int bins[NBIN];
            u64 skey[PHYS(CAPC - 1) + 2];
            float4 sbox[CAPC];
            float sarea[CAPC];
        } a;
        u64 tkey[PHYS(2047) + 2];       // topk tail (walk-phase LDS dead by then)
    } u;
    u64 red8[TN / 64];
    u64 bkey;
    float4 bbox;
    int sint[3];    // 0:B  1:cnt  2:degenerate
    u64 bfil;
    int bna, bdone, bacc, tflag;
};

// wave0 selects the bin threshold B into sint[0]; degenerate flag into sint[2].
__device__ __forceinline__ void select_bin(const int* bins, int* sint, int tid, int lane) {
    if (tid < 64) {
        int lsum[18];
        int tot = 0;
#pragma unroll
        for (int k = 0; k < 18; ++k) { lsum[k] = bins[tid * 18 + k]; tot += lsum[k]; }
        int pfx = tot;
#pragma unroll
        for (int off = 1; off < 64; off <<= 1) {
            int o = __shfl_up(pfx, off, 64);
            if (lane >= off) pfx += o;
        }
        const int totalAll = __shfl(pfx, 63, 64);
        const int sufAbove = totalAll - pfx;
        const int tgt = totalAll < TARGET ? totalAll : TARGET;
        int run = 0, b1 = -1, b2 = 1 << 30;
#pragma unroll
        for (int k = 17; k >= 0; --k) {
            run += lsum[k];
            int suf = sufAbove + run;
            int b = tid * 18 + k;
            if (suf >= tgt && b > b1) b1 = b;
            if (suf <= CAPC && b < b2) b2 = b;
        }
#pragma unroll
        for (int off = 1; off < 64; off <<= 1) {
            int o1 = __shfl_xor(b1, off, 64); if (o1 > b1) b1 = o1;
            int o2 = __shfl_xor(b2, off, 64); if (o2 < b2) b2 = o2;
        }
        if (lane == 0) {
            sint[0] = b1 > b2 ? b1 : b2;
            sint[2] = (b2 == (1 << 30)) ? 1 : 0;
        }
    }
}

// hybrid bitonic sort-512 desc, 2 keys/thread (TN=256): j==1 in-thread,
// 2<=j<=64 via __shfl_xor(j>>1), only j in {128,256} via LDS (3 stages).
__device__ __forceinline__ void sort512_2k(u64* skey, int tid) {
    const int i0 = tid << 1, i1 = i0 | 1;
    u64 k0 = skey[PHYS(i0)], k1 = skey[PHYS(i1)];
    for (int kk2 = 2; kk2 <= CAPC; kk2 <<= 1) {
        for (int j = kk2 >> 1; j > 0; j >>= 1) {
            if (j >= 128) {
                skey[PHYS(i0)] = k0; skey[PHYS(i1)] = k1;
                __syncthreads();
                u64 o0 = skey[PHYS(i0 ^ j)], o1 = skey[PHYS(i1 ^ j)];
                __syncthreads();
                k0 = bsel(k0, o0, i0, kk2, j);
                k1 = bsel(k1, o1, i1, kk2, j);
            } else if (j >= 2) {
                u64 o0 = __shfl_xor(k0, j >> 1, 64);
                u64 o1 = __shfl_xor(k1, j >> 1, 64);
                k0 = bsel(k0, o0, i0, kk2, j);
                k1 = bsel(k1, o1, i1, kk2, j);
            } else {
                bool mx0 = ((i0 & kk2) == 0);
                u64 mx = umx(k0, k1), mn = umn(k0, k1);
                k0 = mx0 ? mx : mn; k1 = mx0 ? mn : mx;
            }
        }
    }
    skey[PHYS(i0)] = k0; skey[PHYS(i1)] = k1;   // last LDS read was pre-barrier: safe
}

// Kernel 1: softmax + threshold -> scores[N][NC][A]; SSD decode -> boxes; zero imgctr.
__global__ __launch_bounds__(256) void preprocess_kernel(
    const float* __restrict__ cls, const float* __restrict__ reg,
    const float* __restrict__ anc, float4* __restrict__ boxes,
    float* __restrict__ scores, int* __restrict__ imgctr) {
    __shared__ __align__(16) float lcls[256 * NCLS];
    const int tid = threadIdx.x;
    const int t = blockIdx.x * 256 + tid;

    if (blockIdx.x == 0 && tid < N_IMG) imgctr[tid] = 0;   // ws is poisoned: must zero

    const float4* src = (const float4*)(cls + (size_t)blockIdx.x * (256 * NCLS));
    float4* dst = (float4*)lcls;
    for (int i = tid; i < (256 * NCLS) / 4; i += 256) dst[i] = src[i];
    __syncthreads();

    const int n = t >> 14;
    const int a = t & (A - 1);
    const float* c = lcls + tid * NCLS;
    float z[NCLS];
    float m = -1e30f;
#pragma unroll
    for (int k = 0; k < NCLS; ++k) { z[k] = c[k]; m = fmaxf(m, z[k]); }
    float s = 0.f;
#pragma unroll
    for (int k = 0; k < NCLS; ++k) { z[k] = expf(z[k] - m); s += z[k]; }
    const float inv = 1.f / s;
#pragma unroll
    for (int k = 0; k < NC; ++k) {
        float p = z[k + 1] * inv;
        scores[(((size_t)n * NC + k) << 14) + a] = (p > PROB_THR) ? p : -1.f;
    }

    const float4 l4 = ((const float4*)reg)[t];
    const float4 an = ((const float4*)anc)[a];
    const float cx = an.x + l4.x * 0.1f * an.z;
    const float cy = an.y + l4.y * 0.1f * an.w;
    const float w  = an.z * expf(l4.z * 0.2f);
    const float h  = an.w * expf(l4.w * 0.2f);
    float x0 = fminf(fmaxf(cx - 0.5f * w, 0.f), 1.f);
    float y0 = fminf(fmaxf(cy - 0.5f * h, 0.f), 1.f);
    float x1 = fminf(fmaxf(cx + 0.5f * w, 0.f), 1.f);
    float y1 = fminf(fmaxf(cy + 0.5f * h, 0.f), 1.f);
    boxes[t] = make_float4(x0, y0, x1, y1);
}

// Kernel 2: one workgroup per (n,ci): hist-select -> sort-512 -> wave0 lazy walk;
// last block of each image runs the per-image top-100 (bitonic-2048, 8 keys/thread).
__global__ __launch_bounds__(TN) void nms_kernel(
    const float4* __restrict__ boxes, const float* __restrict__ scores,
    float* __restrict__ rows, float* __restrict__ out, int* __restrict__ imgctr) {
    __shared__ SMem sm;

    const int blk = blockIdx.x, n = blk / NC, ci = blk % NC;
    const int tid = threadIdx.x, lane = tid & 63, w = tid >> 6;
    const float* gs = scores + ((size_t)blk << 14);
    const float4* gb = boxes + ((size_t)n << 14);
    float* grows = rows + (size_t)blk * 600;

    // scores -> registers (coalesced float4)
    float sc[NSLOT];
    const float4* gs4 = (const float4*)gs;
#pragma unroll
    for (int k = 0; k < NSLOT / 4; ++k) {
        float4 v = gs4[tid + (k << 8)];
        sc[k * 4 + 0] = v.x; sc[k * 4 + 1] = v.y; sc[k * 4 + 2] = v.z; sc[k * 4 + 3] = v.w;
    }

    float4 accA, accB;
    float arA = 0.f, arB = 0.f;
    int na = 0;
    u64 filter = ~0ull;
    bool done = false;

    while (!done && na < TOPK) {
        // ---- filtered histogram ----
        for (int i = tid; i < NBIN; i += TN) sm.u.a.bins[i] = 0;
        if (tid == 0) { sm.sint[1] = 0; sm.sint[2] = 0; }
        __syncthreads();
#pragma unroll
        for (int t = 0; t < NSLOT; ++t) {
            float s = sc[t];
            if (s > 0.f) {
                u64 kk = pk(s, AIDX(t));
                if (kk < filter) atomicAdd(&sm.u.a.bins[binOf(s)], 1);
            }
        }
        __syncthreads();

        select_bin(sm.u.a.bins, sm.sint, tid, lane);
        __syncthreads();
        const int B = sm.sint[0];

        if (!sm.sint[2]) {
            // ---- compact keys of bins >= B (ballot-aggregated; order fixed by sort) ----
#pragma unroll
            for (int t = 0; t < NSLOT; ++t) {
                float s = sc[t];
                bool pred = false; u64 kk = 0ull;
                if (s > 0.f && binOf(s) >= B) {
                    kk = pk(s, AIDX(t));
                    pred = (kk < filter);
                }
                u64 m = __ballot(pred);
                if (m) {
                    int bse = 0;
                    if (lane == 0) bse = atomicAdd(&sm.sint[1], __popcll(m));
                    bse = __shfl(bse, 0, 64);
                    if (pred) {
                        int sl = bse + __popcll(m & ((1ull << lane) - 1ull));
                        sm.u.a.skey[PHYS(sl)] = kk;
                    }
                }
            }
            __syncthreads();
            const int T = sm.sint[1];
            if (T == 0) break;                       // exhausted
            for (int i = T + tid; i < CAPC; i += TN) sm.u.a.skey[PHYS(i)] = 0ull;
            __syncthreads();

            sort512_2k(sm.u.a.skey, tid);
            __syncthreads();

            // ---- gather candidate boxes + areas in sorted order ----
            for (int p = tid; p < CAPC; p += TN) {
                u64 kk = sm.u.a.skey[PHYS(p)];
                if (kk) {
                    float4 b = gb[upi(kk)];
                    sm.u.a.sbox[p] = b;
                    sm.u.a.sarea[p] = (b.z - b.x) * (b.w - b.y);
                }
            }
            __syncthreads();

            // ---- lazy walk: wave0 only, prefetch depth 2 ----
            if (w == 0) {
                u64 kA = sm.u.a.skey[PHYS(0)], kB = 0ull;
                float4 bA = sm.u.a.sbox[0], bB = bA;
                float aA = sm.u.a.sarea[0], aB = 0.f;
                if (T > 1) { kB = sm.u.a.skey[PHYS(1)]; bB = sm.u.a.sbox[1]; aB = sm.u.a.sarea[1]; }
                for (int p = 0; p < T; ++p) {
                    u64 kk = kA; float4 cb = bA; float ca = aA;
                    kA = kB; bA = bB; aA = aB;
                    int p2 = p + 2;
                    if (p2 < T) { kB = sm.u.a.skey[PHYS(p2)]; bB = sm.u.a.sbox[p2]; aB = sm.u.a.sarea[p2]; }
                    filter = kk;
                    bool kill = false;
                    if (lane < na)      kill = killp(cb, ca, accA, arA);
                    if (lane + 64 < na) kill = kill || killp(cb, ca, accB, arB);
                    if (!__any(kill)) {
                        if (lane == 0) {
                            float* o = grows + na * 6;
                            o[0] = cb.x; o[1] = cb.y; o[2] = cb.z; o[3] = cb.w;
                            o[4] = upv(kk); o[5] = (float)(ci + 1);
                        }
                        if (na < 64) { if (lane == na) { accA = cb; arA = ca; } }
                        else if (lane == na - 64) { accB = cb; arB = ca; }
                        ++na;
                        if (na == TOPK) { done = true; break; }
                    }
                }
                if (lane == 0) { sm.bfil = filter; sm.bna = na; sm.bdone = done ? 1 : 0; }
            }
            __syncthreads();
            filter = sm.bfil; na = sm.bna; done = (sm.bdone != 0);
            // next refill's LDS writes are gated by barriers before any reuse.
        } else {
            // ---- degenerate (one bin > CAPC; never on real data): single extractions ----
            while (na < TOPK) {
                u64 best = 0ull;
#pragma unroll
                for (int t = 0; t < NSLOT; ++t) {
                    float s = sc[t];
                    if (s > 0.f) {
                        u64 kk = pk(s, AIDX(t));
                        if (kk < filter && kk > best) best = kk;
                    }
                }
#pragma unroll
                for (int off = 1; off < 64; off <<= 1) best = umx(best, __shfl_xor(best, off, 64));
                if (lane == 0) sm.red8[w] = best;
                __syncthreads();
                if (tid == 0) {
                    u64 bb = sm.red8[0];
#pragma unroll
                    for (int q = 1; q < TN / 64; ++q) bb = umx(bb, sm.red8[q]);
                    sm.bkey = bb;
                    if (bb) sm.bbox = gb[upi(bb)];
                }
                __syncthreads();
                u64 kk = sm.bkey;
                if (!kk) break;
                filter = kk;
                if (w == 0) {
                    float4 cb = sm.bbox;
                    float ca = (cb.z - cb.x) * (cb.w - cb.y);
                    bool kill = false;
                    if (lane < na)      kill = killp(cb, ca, accA, arA);
                    if (lane + 64 < na) kill = kill || killp(cb, ca, accB, arB);
                    int acc = __any(kill) ? 0 : 1;
                    if (lane == 0) sm.bacc = acc;
                    if (acc) {
                        if (lane == 0) {
                            float* o = grows + na * 6;
                            o[0] = cb.x; o[1] = cb.y; o[2] = cb.z; o[3] = cb.w;
                            o[4] = upv(kk); o[5] = (float)(ci + 1);
                        }
                        if (na < 64) { if (lane == na) { accA = cb; arA = ca; } }
                        else if (lane == na - 64) { accB = cb; arB = ca; }
                    }
                }
                __syncthreads();
                if (sm.bacc) ++na;                   // uniform across block
                __syncthreads();
            }
            break;
        }
    }
    for (int j = na * 6 + tid; j < 600; j += TN) grows[j] = 0.f;

    // ---- last block of each image runs the per-image top-100 ----
    __syncthreads();                                  // all rows stores drained (vmcnt0)
    if (tid == 0) {
        __threadfence();                              // release rows to device scope
        int old = atomicAdd(&imgctr[n], 1);
        sm.tflag = (old == NC - 1) ? 1 : 0;
    }
    __syncthreads();
    if (!sm.tflag) return;
    __threadfence();                                  // acquire other blocks' rows

    const float* base = rows + (size_t)n * (NC * 600);
    u64 k[8];
#pragma unroll
    for (int q = 0; q < 8; ++q) {
        int e = (tid << 3) + q;
        u64 kk = 0ull;
        if (e < 2000) {
            int c2 = e / 100, pos = e - c2 * 100;
            float s = base[c2 * 600 + pos * 6 + 4];
            kk = ((u64)__float_as_uint(s) << 32) | (u64)(0xFFFFFFFFu - (unsigned)(e + 100));
        }
        k[q] = kk;
    }
    for (int kk2 = 2; kk2 <= 2048; kk2 <<= 1) {
        for (int j = kk2 >> 1; j > 0; j >>= 1) {
            if (j >= 512) {                           // cross-wave: LDS (3 stages)
#pragma unroll
                for (int q = 0; q < 8; ++q) sm.u.tkey[PHYS((tid << 3) + q)] = k[q];
                __syncthreads();
#pragma unroll
                for (int q = 0; q < 8; ++q) {
                    int i = (tid << 3) + q;
                    u64 o = sm.u.tkey[PHYS(i ^ j)];
                    k[q] = bsel(k[q], o, i, kk2, j);
                }
                __syncthreads();
            } else if (j >= 8) {                      // in-wave: shuffle
#pragma unroll
                for (int q = 0; q < 8; ++q) {
                    int i = (tid << 3) + q;
                    u64 o = __shfl_xor(k[q], j >> 3, 64);
                    k[q] = bsel(k[q], o, i, kk2, j);
                }
            } else {                                  // in-thread: j in {1,2,4}
                u64 nk[8];
#pragma unroll
                for (int q = 0; q < 8; ++q) nk[q] = k[q];
                if (j == 4) {
#pragma unroll
                    for (int q = 0; q < 8; ++q) k[q] = bsel(nk[q], nk[q ^ 4], (tid << 3) + q, kk2, 4);
                } else if (j == 2) {
#pragma unroll
                    for (int q = 0; q < 8; ++q) k[q] = bsel(nk[q], nk[q ^ 2], (tid << 3) + q, kk2, 2);
                } else {
#pragma unroll
                    for (int q = 0; q < 8; ++q) k[q] = bsel(nk[q], nk[q ^ 1], (tid << 3) + q, kk2, 1);
                }
            }
        }
    }
#pragma unroll
    for (int q = 0; q < 8; ++q) sm.u.tkey[PHYS((tid << 3) + q)] = k[q];
    __syncthreads();

    for (int idx = tid; idx < 600; idx += TN) {
        int r = idx / 6, f = idx - r * 6;
        u64 kk = sm.u.tkey[PHYS(r)];
        float v = 0.f;
        if ((unsigned)(kk >> 32) != 0u) {
            int e = (int)(0xFFFFFFFFu - (unsigned)kk) - 100;
            int c2 = e / 100, pos = e - c2 * 100;
            v = base[c2 * 600 + pos * 6 + f];
        }
        out[(size_t)n * 600 + idx] = v;
    }
}

extern "C" void kernel_launch(void* const* d_in, const int* in_sizes, int n_in,
                              void* d_out, int out_size, void* d_ws, size_t ws_size,
                              hipStream_t stream) {
    const float* cls = (const float*)d_in[0];   // [8,16384,21]
    const float* reg = (const float*)d_in[1];   // [8,16384,4]
    const float* anc = (const float*)d_in[2];   // [16384,4]
    float* out = (float*)d_out;                 // [8,100,6]

    // ws layout (floats): boxes 524288 | scores 2621440 | rows 96000 | imgctr 8 ints
    float* boxes  = (float*)d_ws;
    float* scores = boxes + (size_t)N_IMG * A * 4;
    float* rows   = scores + (size_t)N_IMG * NC * A;
    int*   imgctr = (int*)(rows + (size_t)N_IMG * NC * 600);

    preprocess_kernel<<<(N_IMG * A) / 256, 256, 0, stream>>>(cls, reg, anc, (float4*)boxes, scores, imgctr);
    nms_kernel<<<N_IMG * NC, TN, 0, stream>>>((const float4*)boxes, scores, rows, out, imgctr);
}

// Round 4
// 148.461 us; speedup vs baseline: 1.0941x; 1.0941x over previous
//
#include <hip/hip_runtime.h>

// Detection post-process: softmax -> decode -> per-class LAZY NMS -> top-100.
// N=8 images, A=16384 anchors, C=21 classes (class 0 = background).
//
// Budget model (R8/R9 counters): per iteration ~41us ws-fill (harness, fixed) +
// ~12us preprocess + nms + topk + gaps. R7's nms = 60.4us hw-measured with TN=512.
// R9 lesson: TN=256 -> 1 wave/SIMD -> all LDS/atomic latency exposed -> nms 121us.
// R10: nms reverted to the EXACT R7 structure (TN=512, NSLOT=32, hybrid
// shuffle/LDS bitonic sort-512, all-wave redundant walk, depth-1 prefetch) +
// R9's proven fused last-block-per-image topk tail (threadfence + imgctr atomic;
// 4 keys/thread bitonic-2048, 6 LDS stages). 3 dispatches -> 2.
// Exactness invariants (absmax 0.0 since R1):
//   - u64 key = (score_bits<<32)|~idx  => exact (score desc, idx asc) total order
//   - monotone bin(float bits) => bin-threshold selection is a key-order cut
//   - lazy NMS: dead entries never kill => test pops against accepted set only
//   - division-free EXACT IoU predicate:
//     RN_f32(inter/un) > 0.45f  <=>  (double)inter > ((double)0.45f + 2^-26)*(double)un
//   - topk key = (score_bits<<32)|(0xFFFFFFFF-(flat_j+100)) => exact lax.top_k order

typedef unsigned long long u64;

#define N_IMG 8
#define A     16384
#define NCLS  21
#define NC    20
#define TOPK  100
#define PROB_THR 0.05f

#define TN     512         // nms threads (8 waves; 2/SIMD -> latency hiding. R9: don't lower)
#define NSLOT  32          // scores per thread
#define NBIN   1152        // score-bit bins: (bits>>15)-31385 spans (0.05,1]
#define BINOFF 31385
#define CAPC   512         // chunk capacity (sorted); expected pops ~150-250
#define TARGET 384

#define PHYS(i) ((i) + ((i) >> 4))   // LDS u64 swizzle: breaks power-of-2 strides

#define MIDTHR ((double)0.45f + 0x1p-26)

#define AIDX(t_) ((tid << 2) + (((t_) >> 2) << 11) + ((t_) & 3))

__device__ __forceinline__ u64 pk(float v, int i) {
    return (v > 0.f) ? (((u64)__float_as_uint(v) << 32) | (u64)(unsigned)(~(unsigned)i)) : 0ull;
}
__device__ __forceinline__ float upv(u64 k) { return __uint_as_float((unsigned)(k >> 32)); }
__device__ __forceinline__ int   upi(u64 k) { return (int)(~(unsigned)k); }
__device__ __forceinline__ u64 umx(u64 a, u64 b) { return a > b ? a : b; }
__device__ __forceinline__ u64 umn(u64 a, u64 b) { return a < b ? a : b; }

// bitonic compare-exchange keep-rule for element i at stage (k,j):
// region (i&k)==0 sorts descending; lower partner ((i&j)==0) keeps max there.
__device__ __forceinline__ u64 bsel(u64 mine, u64 other, int i, int k, int j) {
    bool keep_max = ((i & k) == 0) == ((i & j) == 0);
    return keep_max ? umx(mine, other) : umn(mine, other);
}

__device__ __forceinline__ int binOf(float s) {
    int b = (int)(__float_as_uint(s) >> 15) - BINOFF;
    return b < 0 ? 0 : (b > NBIN - 1 ? NBIN - 1 : b);
}

// exact ref predicate: RN(inter/union) > 0.45f
__device__ __forceinline__ bool killp(float4 b, float ab, float4 s, float as_) {
    float lx = fmaxf(s.x, b.x), ly = fmaxf(s.y, b.y);
    float rx = fminf(s.z, b.z), ry = fminf(s.w, b.w);
    float iw = fmaxf(rx - lx, 0.f), ih = fmaxf(ry - ly, 0.f);
    float inter = iw * ih;
    float un = as_ + ab - inter;
    return (double)inter > MIDTHR * (double)un;
}

struct SMem {
    union {
        struct {
            int bins[NBIN];
            u64 skey[PHYS(CAPC - 1) + 2];
            float4 sbox[CAPC];
        } a;
        u64 tkey[PHYS(2047) + 2];       // topk tail (nms-phase LDS dead by then)
    } u;
    u64 red8[TN / 64];
    u64 bkey;
    float4 bbox;
    int sint[3];    // 0:B  1:cnt  2:degenerate
    int tflag;
};

// Kernel 1: softmax + threshold -> scores[N][NC][A]; SSD decode -> boxes; zero imgctr.
__global__ __launch_bounds__(256) void preprocess_kernel(
    const float* __restrict__ cls, const float* __restrict__ reg,
    const float* __restrict__ anc, float4* __restrict__ boxes,
    float* __restrict__ scores, int* __restrict__ imgctr) {
    __shared__ __align__(16) float lcls[256 * NCLS];
    const int tid = threadIdx.x;
    const int t = blockIdx.x * 256 + tid;

    if (blockIdx.x == 0 && tid < N_IMG) imgctr[tid] = 0;   // ws is poisoned: must zero

    const float4* src = (const float4*)(cls + (size_t)blockIdx.x * (256 * NCLS));
    float4* dst = (float4*)lcls;
    for (int i = tid; i < (256 * NCLS) / 4; i += 256) dst[i] = src[i];
    __syncthreads();

    const int n = t >> 14;
    const int a = t & (A - 1);
    const float* c = lcls + tid * NCLS;
    float z[NCLS];
    float m = -1e30f;
#pragma unroll
    for (int k = 0; k < NCLS; ++k) { z[k] = c[k]; m = fmaxf(m, z[k]); }
    float s = 0.f;
#pragma unroll
    for (int k = 0; k < NCLS; ++k) { z[k] = expf(z[k] - m); s += z[k]; }
    const float inv = 1.f / s;
#pragma unroll
    for (int k = 0; k < NC; ++k) {
        float p = z[k + 1] * inv;
        scores[(((size_t)n * NC + k) << 14) + a] = (p > PROB_THR) ? p : -1.f;
    }

    const float4 l4 = ((const float4*)reg)[t];
    const float4 an = ((const float4*)anc)[a];
    const float cx = an.x + l4.x * 0.1f * an.z;
    const float cy = an.y + l4.y * 0.1f * an.w;
    const float w  = an.z * expf(l4.z * 0.2f);
    const float h  = an.w * expf(l4.w * 0.2f);
    float x0 = fminf(fmaxf(cx - 0.5f * w, 0.f), 1.f);
    float y0 = fminf(fmaxf(cy - 0.5f * h, 0.f), 1.f);
    float x1 = fminf(fmaxf(cx + 0.5f * w, 0.f), 1.f);
    float y1 = fminf(fmaxf(cy + 0.5f * h, 0.f), 1.f);
    boxes[t] = make_float4(x0, y0, x1, y1);
}

// Kernel 2: one workgroup per (n, ci). Histogram-select -> sort-512 -> lazy walk.
// Last block of each image additionally runs the per-image top-100.
__global__ __launch_bounds__(TN) void nms_kernel(
    const float4* __restrict__ boxes, const float* __restrict__ scores,
    float* __restrict__ rows, float* __restrict__ out, int* __restrict__ imgctr) {
    __shared__ SMem sm;

    const int blk = blockIdx.x, n = blk / NC, ci = blk % NC;
    const int tid = threadIdx.x, lane = tid & 63, w = tid >> 6;
    const float* gs = scores + ((size_t)blk << 14);
    const float4* gb = boxes + ((size_t)n << 14);
    float* grows = rows + (size_t)blk * 600;

    // scores -> registers (coalesced float4)
    float sc[NSLOT];
    const float4* gs4 = (const float4*)gs;
#pragma unroll
    for (int k = 0; k < NSLOT / 4; ++k) {
        float4 v = gs4[tid + (k << 9)];
        sc[k * 4 + 0] = v.x; sc[k * 4 + 1] = v.y; sc[k * 4 + 2] = v.z; sc[k * 4 + 3] = v.w;
    }

    float4 accA, accB;
    float arA = 0.f, arB = 0.f;
    int na = 0;
    u64 filter = ~0ull;
    bool done = false;

    while (!done && na < TOPK) {
        // ---- filtered histogram ----
        for (int i = tid; i < NBIN; i += TN) sm.u.a.bins[i] = 0;
        if (tid == 0) { sm.sint[1] = 0; sm.sint[2] = 0; }
        __syncthreads();
#pragma unroll
        for (int t = 0; t < NSLOT; ++t) {
            float s = sc[t];
            if (s > 0.f) {
                u64 kk = pk(s, AIDX(t));
                if (kk < filter) atomicAdd(&sm.u.a.bins[binOf(s)], 1);
            }
        }
        __syncthreads();

        // ---- select bin threshold B (wave0) ----
        if (tid < 64) {
            int lsum[18];
            int tot = 0;
#pragma unroll
            for (int k = 0; k < 18; ++k) { lsum[k] = sm.u.a.bins[tid * 18 + k]; tot += lsum[k]; }
            int pfx = tot;
#pragma unroll
            for (int off = 1; off < 64; off <<= 1) {
                int o = __shfl_up(pfx, off, 64);
                if (lane >= off) pfx += o;
            }
            const int totalAll = __shfl(pfx, 63, 64);
            const int sufAbove = totalAll - pfx;
            const int tgt = totalAll < TARGET ? totalAll : TARGET;
            int run = 0, b1 = -1, b2 = 1 << 30;
#pragma unroll
            for (int k = 17; k >= 0; --k) {
                run += lsum[k];
                int suf = sufAbove + run;
                int b = tid * 18 + k;
                if (suf >= tgt && b > b1) b1 = b;
                if (suf <= CAPC && b < b2) b2 = b;
            }
#pragma unroll
            for (int off = 1; off < 64; off <<= 1) {
                int o1 = __shfl_xor(b1, off, 64); if (o1 > b1) b1 = o1;
                int o2 = __shfl_xor(b2, off, 64); if (o2 < b2) b2 = o2;
            }
            if (lane == 0) {
                sm.sint[0] = b1 > b2 ? b1 : b2;
                sm.sint[2] = (b2 == (1 << 30)) ? 1 : 0;
            }
        }
        __syncthreads();
        const int B = sm.sint[0];
        const int degen = sm.sint[2];

        if (!degen) {
            // ---- compact keys of bins >= B (ballot-aggregated; order fixed by sort) ----
#pragma unroll
            for (int t = 0; t < NSLOT; ++t) {
                float s = sc[t];
                bool pred = false; u64 kk = 0ull;
                if (s > 0.f && binOf(s) >= B) {
                    kk = pk(s, AIDX(t));
                    pred = (kk < filter);
                }
                u64 m = __ballot(pred);
                if (m) {
                    int bse = 0;
                    if (lane == 0) bse = atomicAdd(&sm.sint[1], __popcll(m));
                    bse = __shfl(bse, 0, 64);
                    if (pred) {
                        int sl = bse + __popcll(m & ((1ull << lane) - 1ull));
                        sm.u.a.skey[PHYS(sl)] = kk;
                    }
                }
            }
            __syncthreads();
            const int T = sm.sint[1];
            if (T == 0) break;                       // exhausted
            for (int i = T + tid; i < CAPC; i += TN) sm.u.a.skey[PHYS(i)] = 0ull;
            __syncthreads();

            // ---- hybrid bitonic sort 512 u64 desc: __shfl_xor j<=32, LDS j>=64 ----
            {
                u64 myk = sm.u.a.skey[PHYS(tid)];
                for (int kk2 = 2; kk2 <= CAPC; kk2 <<= 1) {
                    for (int j = kk2 >> 1; j > 0; j >>= 1) {
                        u64 other;
                        if (j >= 64) {
                            sm.u.a.skey[PHYS(tid)] = myk;
                            __syncthreads();
                            other = sm.u.a.skey[PHYS(tid ^ j)];
                            __syncthreads();
                        } else {
                            other = __shfl_xor(myk, j, 64);
                        }
                        myk = bsel(myk, other, tid, kk2, j);
                    }
                }
                sm.u.a.skey[PHYS(tid)] = myk;   // last cross-wave read was pre-barrier: safe
            }
            __syncthreads();

            // ---- prefetch candidate boxes in sorted order ----
            for (int p = tid; p < CAPC; p += TN) {
                u64 kk = sm.u.a.skey[PHYS(p)];
                if (kk) sm.u.a.sbox[p] = gb[upi(kk)];
            }
            __syncthreads();

            // ---- lazy walk (all waves redundantly; +1-deep register prefetch) ----
            u64 nk = sm.u.a.skey[PHYS(0)];
            float4 nb = sm.u.a.sbox[0];
            for (int p = 0; p < T; ++p) {
                u64 kk = nk; float4 cb = nb;
                if (p + 1 < T) { nk = sm.u.a.skey[PHYS(p + 1)]; nb = sm.u.a.sbox[p + 1]; }
                filter = kk;
                float ca = (cb.z - cb.x) * (cb.w - cb.y);
                bool kill = false;
                if (lane < na)      kill = killp(cb, ca, accA, arA);
                if (lane + 64 < na) kill = kill || killp(cb, ca, accB, arB);
                if (!__any(kill)) {
                    if (tid == 0) {
                        float* o = grows + na * 6;
                        o[0] = cb.x; o[1] = cb.y; o[2] = cb.z; o[3] = cb.w;
                        o[4] = upv(kk); o[5] = (float)(ci + 1);
                    }
                    if (na < 64) { if (lane == na) { accA = cb; arA = ca; } }
                    else if (lane == na - 64) { accB = cb; arB = ca; }
                    ++na;
                    if (na == TOPK) { done = true; break; }
                }
            }
            // next refill's LDS writes are gated by two barriers before any store,
            // so no race with waves still finishing this walk.
        } else {
            // ---- degenerate (one bin > CAPC; never on real data): single extractions ----
            while (na < TOPK) {
                u64 best = 0ull;
#pragma unroll
                for (int t = 0; t < NSLOT; ++t) {
                    float s = sc[t];
                    if (s > 0.f) {
                        u64 kk = pk(s, AIDX(t));
                        if (kk < filter && kk > best) best = kk;
                    }
                }
#pragma unroll
                for (int off = 1; off < 64; off <<= 1) best = umx(best, __shfl_xor(best, off, 64));
                if (lane == 0) sm.red8[w] = best;
                __syncthreads();
                if (tid == 0) {
                    u64 bb = sm.red8[0];
#pragma unroll
                    for (int q = 1; q < TN / 64; ++q) bb = umx(bb, sm.red8[q]);
                    sm.bkey = bb;
                    if (bb) sm.bbox = gb[upi(bb)];
                }
                __syncthreads();
                u64 kk = sm.bkey;
                if (!kk) break;
                filter = kk;
                float4 cb = sm.bbox;
                float ca = (cb.z - cb.x) * (cb.w - cb.y);
                bool kill = false;
                if (lane < na)      kill = killp(cb, ca, accA, arA);
                if (lane + 64 < na) kill = kill || killp(cb, ca, accB, arB);
                if (!__any(kill)) {
                    if (tid == 0) {
                        float* o = grows + na * 6;
                        o[0] = cb.x; o[1] = cb.y; o[2] = cb.z; o[3] = cb.w;
                        o[4] = upv(kk); o[5] = (float)(ci + 1);
                    }
                    if (na < 64) { if (lane == na) { accA = cb; arA = ca; } }
                    else if (lane == na - 64) { accB = cb; arB = ca; }
                    ++na;
                }
                __syncthreads();
            }
            break;
        }
    }
    for (int j = na * 6 + tid; j < 600; j += TN) grows[j] = 0.f;

    // ---- last block of each image runs the per-image top-100 ----
    __syncthreads();                                  // all rows stores drained (vmcnt0)
    if (tid == 0) {
        __threadfence();                              // release rows to device scope
        int old = atomicAdd(&imgctr[n], 1);
        sm.tflag = (old == NC - 1) ? 1 : 0;
    }
    __syncthreads();
    if (!sm.tflag) return;
    __threadfence();                                  // acquire other blocks' rows

    const float* base = rows + (size_t)n * (NC * 600);
    u64 k[4];
#pragma unroll
    for (int q = 0; q < 4; ++q) {
        int e = (tid << 2) + q;
        u64 kk = 0ull;
        if (e < 2000) {
            int c2 = e / 100, pos = e - c2 * 100;
            float s = base[c2 * 600 + pos * 6 + 4];
            kk = ((u64)__float_as_uint(s) << 32) | (u64)(0xFFFFFFFFu - (unsigned)(e + 100));
        }
        k[q] = kk;
    }
    for (int kk2 = 2; kk2 <= 2048; kk2 <<= 1) {
        for (int j = kk2 >> 1; j > 0; j >>= 1) {
            if (j >= 256) {                           // cross-wave: LDS (6 stages total)
#pragma unroll
                for (int q = 0; q < 4; ++q) sm.u.tkey[PHYS((tid << 2) + q)] = k[q];
                __syncthreads();
#pragma unroll
                for (int q = 0; q < 4; ++q) {
                    int i = (tid << 2) + q;
                    u64 o = sm.u.tkey[PHYS(i ^ j)];
                    k[q] = bsel(k[q], o, i, kk2, j);
                }
                __syncthreads();
            } else if (j >= 4) {                      // in-wave: shuffle (lane ^= j>>2)
#pragma unroll
                for (int q = 0; q < 4; ++q) {
                    int i = (tid << 2) + q;
                    u64 o = __shfl_xor(k[q], j >> 2, 64);
                    k[q] = bsel(k[q], o, i, kk2, j);
                }
            } else {                                  // in-thread: j in {1,2}
                u64 nk[4];
#pragma unroll
                for (int q = 0; q < 4; ++q) nk[q] = k[q];
                if (j == 2) {
#pragma unroll
                    for (int q = 0; q < 4; ++q) k[q] = bsel(nk[q], nk[q ^ 2], (tid << 2) + q, kk2, 2);
                } else {
#pragma unroll
                    for (int q = 0; q < 4; ++q) k[q] = bsel(nk[q], nk[q ^ 1], (tid << 2) + q, kk2, 1);
                }
            }
        }
    }
#pragma unroll
    for (int q = 0; q < 4; ++q) sm.u.tkey[PHYS((tid << 2) + q)] = k[q];
    __syncthreads();

    for (int idx = tid; idx < 600; idx += TN) {
        int r = idx / 6, f = idx - r * 6;
        u64 kk = sm.u.tkey[PHYS(r)];
        float v = 0.f;
        if ((unsigned)(kk >> 32) != 0u) {
            int e = (int)(0xFFFFFFFFu - (unsigned)kk) - 100;
            int c2 = e / 100, pos = e - c2 * 100;
            v = base[c2 * 600 + pos * 6 + f];
        }
        out[(size_t)n * 600 + idx] = v;
    }
}

extern "C" void kernel_launch(void* const* d_in, const int* in_sizes, int n_in,
                              void* d_out, int out_size, void* d_ws, size_t ws_size,
                              hipStream_t stream) {
    const float* cls = (const float*)d_in[0];   // [8,16384,21]
    const float* reg = (const float*)d_in[1];   // [8,16384,4]
    const float* anc = (const float*)d_in[2];   // [16384,4]
    float* out = (float*)d_out;                 // [8,100,6]

    // ws layout (floats): boxes 524288 | scores 2621440 | rows 96000 | imgctr 8 ints
    float* boxes  = (float*)d_ws;
    float* scores = boxes + (size_t)N_IMG * A * 4;
    float* rows   = scores + (size_t)N_IMG * NC * A;
    int*   imgctr = (int*)(rows + (size_t)N_IMG * NC * 600);

    preprocess_kernel<<<(N_IMG * A) / 256, 256, 0, stream>>>(cls, reg, anc, (float4*)boxes, scores, imgctr);
    nms_kernel<<<N_IMG * NC, TN, 0, stream>>>((const float4*)boxes, scores, rows, out, imgctr);
}